// Round 17
// baseline (218.862 us; speedup 1.0000x reference)
//
#include <hip/hip_runtime.h>

#define CI 64
#define CO 128
#define HH 64
#define WW 64
#define OH 62
#define OW 62
#define XTW 66          // padded row width in LDS: 64 real cols + 2 zero cols
#define RB (XTW * 64)   // ushorts per staged input row = 4224 (8448 B)
#define ROWS_OUT 8      // output rows per block (2 per wave, 8 waves)
#define ROWS_IN 10      // staged input rows per block
#define NBLK_X 8        // ceil(62/8); last block masks oh>=62

typedef __attribute__((ext_vector_type(8))) short short8x;
typedef __attribute__((ext_vector_type(16))) float f32x16;

// Weight scratch in a module device-global (not d_ws); wprep rewrites it
// every launch (idempotent, graph-capture safe).  ~3 us, L2-resident.
__device__ __attribute__((aligned(16))) ushort g_wt[9 * CO * CI];   // [tap][co][ci] bf16

__device__ __forceinline__ ushort bf16rne(float f) {
    unsigned u = __builtin_bit_cast(unsigned, f);
    u += 0x7fffu + ((u >> 16) & 1u);
    return (ushort)(u >> 16);
}

__global__ __launch_bounds__(256)
void wprep(const float* __restrict__ w) {
    const int idx = blockIdx.x * 256 + threadIdx.x;   // 73728 total
    const int kk = idx >> 13;
    const int rem = idx & 8191;
    const int co = rem >> 6, ci = rem & 63;
    g_wt[idx] = bf16rne(w[(co * 64 + ci) * 9 + kk]);
}

// r16 winner widened to 512 threads / 8-row blocks.  8 waves = co-half x
// rw(0..3), each wave 2 rows (rw, rw+4) -> per-wave regs and weight
// amortization IDENTICAL to r16 (2 waves/SIMD cap unchanged), but:
//  - staging redundancy 1.5x -> 1.25x (10 in / 8 out rows)
//  - per-(b,co) store runs double: 8 contiguous oh rows = 1984 B streams
//  - 8 intra-block waves interleave stage/compute/store phases per CU
// Staging: wave (g=wv>>2, cb=wv&3) stages rows 4g..4g+3 (phase 1) and row
// 8+g (deferred: loads issued before taps kr=0 which need only rows 0..7,
// cvt+ds_write after tap 2, barrier, taps 3..8).  Swizzle/K-loop/epilogue
// byte-identical to the r15/r16-verified patterns.
__global__ __launch_bounds__(512, 2)
void conv_fused(const float* __restrict__ x, const float* __restrict__ bias,
                float* __restrict__ out) {
    __shared__ ushort Xl[ROWS_IN * RB];   // 84,480 B -> 1 block/CU
    __shared__ float  sB[CO];

    const int tid = threadIdx.x;
    const int wv = tid >> 6, L = tid & 63, l31 = L & 31, q = L >> 5;
    const int h = wv >> 2;           // co half: co base = h*64
    const int rw = wv & 3;           // wave's first row; second = rw+4
    const int b = blockIdx.y, oh0 = blockIdx.x * ROWS_OUT;

    if (tid < CO) sB[tid] = bias[tid];

    // ---- tap-0 A-fragment loads first (verified layout: m=l31, k=q*8+j) ----
    const ushort* wbase = g_wt + (h * 64 + l31) * 64 + q * 8;
    short8x wbuf[2][8];   // [dbuf][m*4+s]
    #pragma unroll
    for (int m = 0; m < 2; ++m)
        #pragma unroll
        for (int ss = 0; ss < 4; ++ss)
            wbuf[0][m * 4 + ss] = *(const short8x*)(wbase + m * 2048 + ss * 16);

    // ---- zero-pad pixels 64,65 of ALL 10 staged rows (160 x uint4) ----
    if (tid < 160) {
        const int r10 = tid >> 4, c = tid & 15;
        const int px = 64 + (c >> 3), slot = c & 7;
        const uint4 z{0, 0, 0, 0};
        *reinterpret_cast<uint4*>(&Xl[(r10 * XTW + px) * 64 + slot * 8]) = z;
    }

    // ---- phase 1: stage rows 0..7; wave (g,cb) does rows 4g..4g+3, ci 16cb ----
    const int w = L;
    const int g = wv >> 2, cb = wv & 3;
    const size_t cibase = (size_t)(b * 64 + cb * 16) * (HH * WW);
    #pragma unroll
    for (int r = 0; r < 4; ++r) {
        const int r10 = 4 * g + r;
        int ir = oh0 + r10;
        if (ir > 63) ir = 63;                 // last strip clamp (dummy)
        const float* src = x + cibase + (size_t)ir * WW + w;
        union { ushort u[8]; uint4 v; } p0, p1;
        #pragma unroll
        for (int k = 0; k < 8; ++k)
            p0.u[k] = bf16rne(src[(size_t)k * (HH * WW)]);
        #pragma unroll
        for (int k = 0; k < 8; ++k)
            p1.u[k] = bf16rne(src[(size_t)(8 + k) * (HH * WW)]);
        const int pl = r10 * XTW + w, key = pl & 7;
        ushort* dst = &Xl[pl * 64];
        *reinterpret_cast<uint4*>(dst + (((2 * cb)     ^ key) * 8)) = p0.v;
        *reinterpret_cast<uint4*>(dst + (((2 * cb + 1) ^ key) * 8)) = p1.v;
    }

    f32x16 acc[2][2][2];   // [row2][mt][nt] -- 128 AGPRs
    #pragma unroll
    for (int r2 = 0; r2 < 2; ++r2)
        #pragma unroll
        for (int i = 0; i < 2; ++i)
            #pragma unroll
            for (int jj = 0; jj < 2; ++jj)
                #pragma unroll
                for (int r = 0; r < 16; ++r) acc[r2][i][jj][r] = 0.f;

    __syncthreads();   // barrier 1: rows 0..7 + pads visible

    // ---- issue row (8+g) loads NOW (latency hides under taps kr=0) ----
    float v89[16];
    {
        int ir = oh0 + 8 + g;
        if (ir > 63) ir = 63;                 // last strip clamp (dummy)
        const float* src = x + cibase + (size_t)ir * WW + w;
        #pragma unroll
        for (int k = 0; k < 16; ++k)
            v89[k] = src[(size_t)k * (HH * WW)];
    }

    // ---- taps kr=0 (kk=0..2): rows rw, rw+4 -- staged in phase 1 ----
    #pragma unroll
    for (int kk = 0; kk < 3; ++kk) {
        const short8x* wf = wbuf[kk & 1];
        {   // prefetch next tap's A
            const ushort* nb = wbase + (kk + 1) * (CO * CI);
            #pragma unroll
            for (int m = 0; m < 2; ++m)
                #pragma unroll
                for (int ss = 0; ss < 4; ++ss)
                    wbuf[(kk + 1) & 1][m * 4 + ss] = *(const short8x*)(nb + m * 2048 + ss * 16);
        }
        const int kc = kk;
        const int pBa = rw * XTW + kc + l31;              // row rw
        const int pBb = (rw + 4) * XTW + kc + l31;        // row rw+4
        const ushort* bPa = Xl + pBa * 64;
        const ushort* bPb = Xl + pBb * 64;
        const int f0a = pBa & 7, f0b = pBb & 7;
        #pragma unroll
        for (int ss = 0; ss < 4; ++ss) {
            const int oba = (((ss * 2 + q) ^ f0a) * 8);
            const int obb = (((ss * 2 + q) ^ f0b) * 8);
            short8x a0 = *(const short8x*)(bPa + oba);
            short8x a1 = *(const short8x*)(bPa + 32 * 64 + oba);
            short8x c0 = *(const short8x*)(bPb + obb);
            short8x c1 = *(const short8x*)(bPb + 32 * 64 + obb);
            acc[0][0][0] = __builtin_amdgcn_mfma_f32_32x32x16_bf16(wf[ss],     a0, acc[0][0][0], 0, 0, 0);
            acc[0][0][1] = __builtin_amdgcn_mfma_f32_32x32x16_bf16(wf[ss],     a1, acc[0][0][1], 0, 0, 0);
            acc[0][1][0] = __builtin_amdgcn_mfma_f32_32x32x16_bf16(wf[4 + ss], a0, acc[0][1][0], 0, 0, 0);
            acc[0][1][1] = __builtin_amdgcn_mfma_f32_32x32x16_bf16(wf[4 + ss], a1, acc[0][1][1], 0, 0, 0);
            acc[1][0][0] = __builtin_amdgcn_mfma_f32_32x32x16_bf16(wf[ss],     c0, acc[1][0][0], 0, 0, 0);
            acc[1][0][1] = __builtin_amdgcn_mfma_f32_32x32x16_bf16(wf[ss],     c1, acc[1][0][1], 0, 0, 0);
            acc[1][1][0] = __builtin_amdgcn_mfma_f32_32x32x16_bf16(wf[4 + ss], c0, acc[1][1][0], 0, 0, 0);
            acc[1][1][1] = __builtin_amdgcn_mfma_f32_32x32x16_bf16(wf[4 + ss], c1, acc[1][1][1], 0, 0, 0);
        }
    }

    // ---- cvt + ds_write row 8+g (loads drained under the taps) ----
    {
        union { ushort u[8]; uint4 v; } p0, p1;
        #pragma unroll
        for (int k = 0; k < 8; ++k) p0.u[k] = bf16rne(v89[k]);
        #pragma unroll
        for (int k = 0; k < 8; ++k) p1.u[k] = bf16rne(v89[8 + k]);
        const int pl = (8 + g) * XTW + w, key = pl & 7;
        ushort* dst = &Xl[pl * 64];
        *reinterpret_cast<uint4*>(dst + (((2 * cb)     ^ key) * 8)) = p0.v;
        *reinterpret_cast<uint4*>(dst + (((2 * cb + 1) ^ key) * 8)) = p1.v;
    }

    __syncthreads();   // barrier 2: rows 8,9 visible

    // ---- taps kk=3..8 (kr=1,2) ----
    #pragma unroll
    for (int kk = 3; kk < 9; ++kk) {
        const short8x* wf = wbuf[kk & 1];
        if (kk < 8) {   // prefetch next tap's A
            const ushort* nb = wbase + (kk + 1) * (CO * CI);
            #pragma unroll
            for (int m = 0; m < 2; ++m)
                #pragma unroll
                for (int ss = 0; ss < 4; ++ss)
                    wbuf[(kk + 1) & 1][m * 4 + ss] = *(const short8x*)(nb + m * 2048 + ss * 16);
        }
        const int kr = kk / 3, kc = kk - kr * 3;
        const int pBa = (rw + kr) * XTW + kc + l31;       // row rw
        const int pBb = (rw + 4 + kr) * XTW + kc + l31;   // row rw+4
        const ushort* bPa = Xl + pBa * 64;
        const ushort* bPb = Xl + pBb * 64;
        const int f0a = pBa & 7, f0b = pBb & 7;
        #pragma unroll
        for (int ss = 0; ss < 4; ++ss) {
            const int oba = (((ss * 2 + q) ^ f0a) * 8);
            const int obb = (((ss * 2 + q) ^ f0b) * 8);
            short8x a0 = *(const short8x*)(bPa + oba);
            short8x a1 = *(const short8x*)(bPa + 32 * 64 + oba);
            short8x c0 = *(const short8x*)(bPb + obb);
            short8x c1 = *(const short8x*)(bPb + 32 * 64 + obb);
            acc[0][0][0] = __builtin_amdgcn_mfma_f32_32x32x16_bf16(wf[ss],     a0, acc[0][0][0], 0, 0, 0);
            acc[0][0][1] = __builtin_amdgcn_mfma_f32_32x32x16_bf16(wf[ss],     a1, acc[0][0][1], 0, 0, 0);
            acc[0][1][0] = __builtin_amdgcn_mfma_f32_32x32x16_bf16(wf[4 + ss], a0, acc[0][1][0], 0, 0, 0);
            acc[0][1][1] = __builtin_amdgcn_mfma_f32_32x32x16_bf16(wf[4 + ss], a1, acc[0][1][1], 0, 0, 0);
            acc[1][0][0] = __builtin_amdgcn_mfma_f32_32x32x16_bf16(wf[ss],     c0, acc[1][0][0], 0, 0, 0);
            acc[1][0][1] = __builtin_amdgcn_mfma_f32_32x32x16_bf16(wf[ss],     c1, acc[1][0][1], 0, 0, 0);
            acc[1][1][0] = __builtin_amdgcn_mfma_f32_32x32x16_bf16(wf[4 + ss], c0, acc[1][1][0], 0, 0, 0);
            acc[1][1][1] = __builtin_amdgcn_mfma_f32_32x32x16_bf16(wf[4 + ss], c1, acc[1][1][1], 0, 0, 0);
        }
    }

    // ---- terminal epilogue (verified r0 mapping), both rows ----
    #pragma unroll
    for (int r2 = 0; r2 < 2; ++r2) {
        const int oh = oh0 + rw + 4 * r2;
        if (oh < OH) {
            #pragma unroll
            for (int mt = 0; mt < 2; ++mt)
                #pragma unroll
                for (int nt = 0; nt < 2; ++nt) {
                    const int col = nt * 32 + l31;
                    if (col < OW) {
                        #pragma unroll
                        for (int reg = 0; reg < 16; ++reg) {
                            const int co = h * 64 + mt * 32 + 4 * q + (reg & 3) + 8 * (reg >> 2);
                            out[(((size_t)b * CO + co) * OH + oh) * OW + col] = acc[r2][mt][nt][reg] + sB[co];
                        }
                    }
                }
        }
    }
}

extern "C" void kernel_launch(void* const* d_in, const int* in_sizes, int n_in,
                              void* d_out, int out_size, void* d_ws, size_t ws_size,
                              hipStream_t stream) {
    const float* x    = (const float*)d_in[0];
    const float* wgt  = (const float*)d_in[1];
    const float* bias = (const float*)d_in[2];
    float* out = (float*)d_out;

    wprep<<<dim3(288), 256, 0, stream>>>(wgt);
    conv_fused<<<dim3(NBLK_X, 64), 512, 0, stream>>>(x, bias, out);
}